// Round 8
// baseline (299.193 us; speedup 1.0000x reference)
//
#include <hip/hip_runtime.h>
#include <math.h>

#define NBATCH 4
#define NSEQ   1024
#define DMODEL 512
#define NH     8
#define DH     64
#define MROWS  (NBATCH*NSEQ)   // 4096
#define MHALF  (DH/2)          // 32

typedef __attribute__((ext_vector_type(8))) short bf16x8;
typedef __attribute__((ext_vector_type(4))) float floatx4;

// round-to-nearest-even fp32 -> bf16 (finite inputs only)
__device__ __forceinline__ ushort f2bf(float f) {
    union { float f; uint u; } v; v.f = f;
    uint r = v.u + 0x7fffu + ((v.u >> 16) & 1u);
    return (ushort)(r >> 16);
}

// ---------------------------------------------------------------------------
// Kernel 0 (fused prep): blocks 0..1023 angles (block 0 also zeroes the
// split-K counters), 1024..2047 x->bf16, 2048..2303 weight transpose-cast
// into Wt[n_global][k] bf16 (0..511 Wq, 512..1023 Wk, 1024..1535 Wv,
// 1536..2047 Wo).
// ---------------------------------------------------------------------------
__global__ __launch_bounds__(256) void prep_kernel(
    const float* __restrict__ pos, const float* __restrict__ freqs,
    const float* __restrict__ x,
    const float* __restrict__ Wq, const float* __restrict__ Wk,
    const float* __restrict__ Wv, const float* __restrict__ Wo,
    float* __restrict__ cosT, float* __restrict__ sinT,
    ushort* __restrict__ xb, ushort* __restrict__ Wt,
    uint* __restrict__ cnt)
{
    __shared__ float T[64][65];
    const int bid = blockIdx.x;
    const int tid = threadIdx.x;

    if (bid < 1024) {
        if (bid == 0) { cnt[tid] = 0u; cnt[tid + 256] = 0u; }  // 512 counters
        int idx = bid * 256 + tid;
        int m = idx & 31;
        int n = (idx >> 5) & 1023;
        int h = idx >> 15;
        float a = pos[n*2+0] * freqs[(h*MHALF+m)*2+0]
                + pos[n*2+1] * freqs[(h*MHALF+m)*2+1];
        cosT[idx] = cosf(a);
        sinT[idx] = sinf(a);
    } else if (bid < 2048) {
        int idx = ((bid - 1024) * 256 + tid) * 8;
        float4 a = *(const float4*)&x[idx];
        float4 b = *(const float4*)&x[idx+4];
        uint4 pk;
        pk.x = (uint)f2bf(a.x) | ((uint)f2bf(a.y) << 16);
        pk.y = (uint)f2bf(a.z) | ((uint)f2bf(a.w) << 16);
        pk.z = (uint)f2bf(b.x) | ((uint)f2bf(b.y) << 16);
        pk.w = (uint)f2bf(b.z) | ((uint)f2bf(b.w) << 16);
        *(uint4*)&xb[idx] = pk;
    } else {
        int b2 = bid - 2048;               // 0..255
        int n0g = (b2 & 31) * 64;          // 0..2047
        int k0  = (b2 >> 5) * 64;
        int mat = n0g >> 9;
        const float* W = (mat == 0) ? Wq : ((mat == 1) ? Wk : ((mat == 2) ? Wv : Wo));
        int n0 = n0g & 511;
        int c = tid & 63, r = tid >> 6;
        #pragma unroll
        for (int i = 0; i < 16; i++)
            T[r + i*4][c] = W[(k0 + r + i*4) * DMODEL + n0 + c];
        __syncthreads();
        int nl = tid >> 2;
        int kg = tid & 3;
        #pragma unroll
        for (int g = 0; g < 4; g++) {
            int kl = kg * 16 + g * 4;
            uint2 pk;
            pk.x = (uint)f2bf(T[kl+0][nl]) | ((uint)f2bf(T[kl+1][nl]) << 16);
            pk.y = (uint)f2bf(T[kl+2][nl]) | ((uint)f2bf(T[kl+3][nl]) << 16);
            *(uint2*)&Wt[(size_t)(n0g + nl) * DMODEL + k0 + kl] = pk;
        }
    }
}

// ---------------------------------------------------------------------------
// Kernel 1: QKV GEMM via bf16 MFMA + rotary + bf16 pack + V-transpose.
// (R3/R6 64x64-tile version — verified; grid (24,64) = 1536 blocks.)
// ---------------------------------------------------------------------------
__global__ __launch_bounds__(256) void qkv_gemm(
    const ushort* __restrict__ xb, const ushort* __restrict__ Wt,
    const float* __restrict__ cosT, const float* __restrict__ sinT,
    ushort* __restrict__ Qb, ushort* __restrict__ Kb, ushort* __restrict__ Vt)
{
    __shared__ ushort As[64 * 40];
    __shared__ ushort Bs[64 * 40];
    __shared__ float  Cs[64][65];

    const int cb = blockIdx.x;           // 0..23
    const int rb = blockIdx.y;           // 0..63
    const int mat = cb >> 3;             // 0=Q 1=K 2=V
    const int c0 = (cb & 7) * 64;
    const int r0 = rb * 64;
    const int ng0 = mat * 512 + c0;

    const int tid = threadIdx.x;
    const int w = tid >> 6, l = tid & 63;
    const int lr = l & 15, lg = l >> 4;

    const int srow = tid >> 2;
    const int sgrp = tid & 3;

    floatx4 acc[4];
    #pragma unroll
    for (int nt = 0; nt < 4; nt++) acc[nt] = (floatx4){0.f,0.f,0.f,0.f};

    for (int k0 = 0; k0 < DMODEL; k0 += 32) {
        __syncthreads();
        *(uint4*)&As[srow*40 + sgrp*8] =
            *(const uint4*)&xb[(size_t)(r0 + srow) * DMODEL + k0 + sgrp*8];
        *(uint4*)&Bs[srow*40 + sgrp*8] =
            *(const uint4*)&Wt[(size_t)(ng0 + srow) * DMODEL + k0 + sgrp*8];
        __syncthreads();

        bf16x8 af = *(const bf16x8*)&As[(16*w + lr)*40 + lg*8];
        #pragma unroll
        for (int nt = 0; nt < 4; nt++) {
            bf16x8 bf = *(const bf16x8*)&Bs[(nt*16 + lr)*40 + lg*8];
            acc[nt] = __builtin_amdgcn_mfma_f32_16x16x32_bf16(af, bf, acc[nt], 0, 0, 0);
        }
    }

    __syncthreads();
    #pragma unroll
    for (int nt = 0; nt < 4; nt++)
        #pragma unroll
        for (int r = 0; r < 4; r++)
            Cs[16*w + lg*4 + r][nt*16 + lr] = acc[nt][r];
    __syncthreads();

    const int tx = tid & 15, ty = tid >> 4;
    const int dbase = tx * 4;
    const int head = c0 >> 6;

    if (mat == 2) {
        int rowbase = r0 + ty * 4;
        int b = rowbase >> 10, n0 = rowbase & 1023;
        size_t vbase = (size_t)(b * NH + head) * DH;
        #pragma unroll
        for (int j = 0; j < 4; j++) {
            ushort us[4];
            #pragma unroll
            for (int i = 0; i < 4; i++) us[i] = f2bf(Cs[ty*4 + i][tx*4 + j]);
            uint2 pk;
            pk.x = (uint)us[0] | ((uint)us[1] << 16);
            pk.y = (uint)us[2] | ((uint)us[3] << 16);
            *(uint2*)&Vt[(vbase + dbase + j) * NSEQ + n0] = pk;
        }
    } else {
        ushort* dst = (mat == 0) ? Qb : Kb;
        #pragma unroll
        for (int i = 0; i < 4; i++) {
            int row = r0 + ty * 4 + i;
            int b = row >> 10, n = row & 1023;
            float v[4];
            #pragma unroll
            for (int p = 0; p < 2; p++) {
                int de = dbase + 2 * p;
                int m = de >> 1;
                float c = cosT[(head * NSEQ + n) * MHALF + m];
                float s = sinT[(head * NSEQ + n) * MHALF + m];
                float ve = Cs[ty*4 + i][tx*4 + 2*p];
                float vo = Cs[ty*4 + i][tx*4 + 2*p + 1];
                v[2*p]     = ve * c - vo * s;
                v[2*p + 1] = ve * s + vo * c;
            }
            uint2 pk;
            pk.x = (uint)f2bf(v[0]) | ((uint)f2bf(v[1]) << 16);
            pk.y = (uint)f2bf(v[2]) | ((uint)f2bf(v[3]) << 16);
            *(uint2*)&dst[((size_t)(b * NH + head) * NSEQ + n) * DH + dbase] = pk;
        }
    }
}

// ---------------------------------------------------------------------------
// Kernel 2: flash attention, split-K x2, no-rescale softmax, with fused
// split-K fixup: the last-finishing z-block of each (q-tile, bh) pair merges
// its in-register O with the other slice's Opart and writes Obb bf16 directly
// (device-scope atomic counter + __threadfence release/acquire — standard
// StreamK fixup; avoids the combine kernel and 2/3 of the Opart traffic).
// Grid (16, 32, 2) = 1024 blocks, 4 blocks/CU (27.6 KB LDS).
// Scores |s| <~ 8 << 88 so exp2(c*s) cannot overflow; p,l unnormalized.
// ---------------------------------------------------------------------------
__global__ __launch_bounds__(256, 4) void attn_kernel(
    const ushort* __restrict__ Qb, const ushort* __restrict__ Kb,
    const ushort* __restrict__ Vt, float* __restrict__ Opart,
    float* __restrict__ Lsum, uint* __restrict__ cnt,
    ushort* __restrict__ Obb)
{
    __shared__ ushort Ks[64 * 72];
    __shared__ ushort Vs[64 * 72];
    __shared__ ushort Ps[64 * 72];
    __shared__ int lastflag;

    const int tid = threadIdx.x;
    const int w = tid >> 6, l = tid & 63;
    const int lr = l & 15, lg = l >> 4;
    const int bh = blockIdx.y, q0 = blockIdx.x * 64;
    const int z = blockIdx.z, jt0 = z * 8;

    const ushort* Qg = Qb + (size_t)bh * NSEQ * DH;
    const ushort* Kg = Kb + (size_t)bh * NSEQ * DH;
    const ushort* Vg = Vt + (size_t)bh * DH * NSEQ;

    bf16x8 qf[2];
    #pragma unroll
    for (int ks = 0; ks < 2; ks++)
        qf[ks] = *(const bf16x8*)(Qg + (size_t)(q0 + 16*w + lr) * DH + ks*32 + lg*8);

    floatx4 ot[4];
    #pragma unroll
    for (int i = 0; i < 4; i++) ot[i] = (floatx4){0.f, 0.f, 0.f, 0.f};
    float rsum = 0.f;
    const float cexp = 0.2550348550f;    // log2(e)/sqrt(32)

    const int sr = tid >> 2;
    const int sc = (tid & 3) * 16;

    // prefetch first tile
    const ushort* kp = Kg + (size_t)(jt0*64 + sr) * DH + sc;
    uint4 ka  = *(const uint4*)kp;
    uint4 kb2 = *(const uint4*)(kp + 8);
    const ushort* vp = Vg + (size_t)sr * NSEQ + jt0*64 + sc;
    uint4 va  = *(const uint4*)vp;
    uint4 vb2 = *(const uint4*)(vp + 8);

    for (int jt = jt0; jt < jt0 + 8; jt++) {
        __syncthreads();
        *(uint4*)&Ks[sr*72 + sc]     = ka;
        *(uint4*)&Ks[sr*72 + sc + 8] = kb2;
        *(uint4*)&Vs[sr*72 + sc]     = va;
        *(uint4*)&Vs[sr*72 + sc + 8] = vb2;
        __syncthreads();

        if (jt < jt0 + 7) {   // prefetch next tile (uniform branch)
            const ushort* kn = Kg + (size_t)((jt+1)*64 + sr) * DH + sc;
            ka  = *(const uint4*)kn;
            kb2 = *(const uint4*)(kn + 8);
            const ushort* vn = Vg + (size_t)sr * NSEQ + (jt+1)*64 + sc;
            va  = *(const uint4*)vn;
            vb2 = *(const uint4*)(vn + 8);
        }

        // S^T strip (raw scores) -> p = exp2(c*s) -> P^T pack (wave-local)
        #pragma unroll
        for (int jm = 0; jm < 4; jm++) {
            bf16x8 a0 = *(const bf16x8*)&Ks[(jm*16 + lr)*72 + lg*8];
            bf16x8 a1 = *(const bf16x8*)&Ks[(jm*16 + lr)*72 + 32 + lg*8];
            floatx4 s = (floatx4){0.f, 0.f, 0.f, 0.f};
            s = __builtin_amdgcn_mfma_f32_16x16x32_bf16(a0, qf[0], s, 0, 0, 0);
            s = __builtin_amdgcn_mfma_f32_16x16x32_bf16(a1, qf[1], s, 0, 0, 0);
            ushort us[4];
            #pragma unroll
            for (int r = 0; r < 4; r++) {
                float p = exp2f(s[r] * cexp);
                rsum += p;
                us[r] = f2bf(p);
            }
            uint2 pk;
            pk.x = (uint)us[0] | ((uint)us[1] << 16);
            pk.y = (uint)us[2] | ((uint)us[3] << 16);
            *(uint2*)&Ps[(16*w + lr)*72 + jm*16 + lg*4] = pk;
        }

        // PV: O^T[d][q] += V^T[d][j] * P^T[j][q]  (Ps rows wave-local)
        bf16x8 pf[2];
        #pragma unroll
        for (int ks = 0; ks < 2; ks++)
            pf[ks] = *(const bf16x8*)&Ps[(16*w + lr)*72 + ks*32 + lg*8];
        #pragma unroll
        for (int dt = 0; dt < 4; dt++) {
            bf16x8 v0 = *(const bf16x8*)&Vs[(dt*16 + lr)*72 + lg*8];
            bf16x8 v1 = *(const bf16x8*)&Vs[(dt*16 + lr)*72 + 32 + lg*8];
            ot[dt] = __builtin_amdgcn_mfma_f32_16x16x32_bf16(v0, pf[0], ot[dt], 0, 0, 0);
            ot[dt] = __builtin_amdgcn_mfma_f32_16x16x32_bf16(v1, pf[1], ot[dt], 0, 0, 0);
        }
    }

    // reduce l across the 4 lg-groups (disjoint j sets)
    rsum += __shfl_xor(rsum, 16, 64);
    rsum += __shfl_xor(rsum, 32, 64);

    // publish this slice
    const int n = q0 + 16*w + lr;
    const size_t obase = ((size_t)(z * 32 + bh) * NSEQ + n) * DH;
    #pragma unroll
    for (int dt = 0; dt < 4; dt++)
        *(floatx4*)&Opart[obase + dt*16 + lg*4] = ot[dt];
    if (lg == 0)
        Lsum[(size_t)(z * 32 + bh) * NSEQ + n] = rsum;

    __threadfence();                       // release: Opart/Lsum -> device scope
    if (tid == 0)
        lastflag = (int)atomicAdd(&cnt[blockIdx.x * 32 + bh], 1u);
    __syncthreads();

    if (lastflag == 1) {                   // we are the last of the pair
        __threadfence();                   // acquire: invalidate stale cache
        const int zo = 1 - z;
        const size_t obase2 = ((size_t)(zo * 32 + bh) * NSEQ + n) * DH;
        const float lo = Lsum[(size_t)(zo * 32 + bh) * NSEQ + n];
        const float inv = 1.f / (rsum + lo);
        #pragma unroll
        for (int dt = 0; dt < 4; dt++) {
            floatx4 o2 = *(const floatx4*)&Opart[obase2 + dt*16 + lg*4];
            floatx4 s = (ot[dt] + o2) * inv;
            uint2 pk;
            pk.x = (uint)f2bf(s[0]) | ((uint)f2bf(s[1]) << 16);
            pk.y = (uint)f2bf(s[2]) | ((uint)f2bf(s[3]) << 16);
            *(uint2*)&Obb[((size_t)bh * NSEQ + n) * DH + dt*16 + lg*4] = pk;
        }
    }
}

// ---------------------------------------------------------------------------
// Kernel 3: output projection via bf16 MFMA (R4/R6 version — verified).
// A gathered from Obb [bh][n][d] bf16; B = Wt rows 1536..2047. Grid (8,64).
// ---------------------------------------------------------------------------
__global__ __launch_bounds__(256) void out_gemm(
    const ushort* __restrict__ Obb, const ushort* __restrict__ Wt,
    float* __restrict__ out)
{
    __shared__ ushort As[64 * 40];
    __shared__ ushort Bs[64 * 40];
    __shared__ float  Cs[64][65];

    const int cb = blockIdx.x;
    const int rb = blockIdx.y;
    const int c0 = cb * 64, r0 = rb * 64;

    const int tid = threadIdx.x;
    const int w = tid >> 6, l = tid & 63;
    const int lr = l & 15, lg = l >> 4;
    const int srow = tid >> 2;
    const int sgrp = tid & 3;

    const int arow = r0 + srow;
    const int b = arow >> 10, n = arow & 1023;

    floatx4 acc[4];
    #pragma unroll
    for (int nt = 0; nt < 4; nt++) acc[nt] = (floatx4){0.f,0.f,0.f,0.f};

    for (int k0 = 0; k0 < DMODEL; k0 += 32) {
        int h = k0 >> 6;
        int d0 = k0 & 63;
        __syncthreads();
        *(uint4*)&As[srow*40 + sgrp*8] =
            *(const uint4*)&Obb[((size_t)(b * NH + h) * NSEQ + n) * DH + d0 + sgrp*8];
        *(uint4*)&Bs[srow*40 + sgrp*8] =
            *(const uint4*)&Wt[(size_t)(1536 + c0 + srow) * DMODEL + k0 + sgrp*8];
        __syncthreads();

        bf16x8 af = *(const bf16x8*)&As[(16*w + lr)*40 + lg*8];
        #pragma unroll
        for (int nt = 0; nt < 4; nt++) {
            bf16x8 bf = *(const bf16x8*)&Bs[(nt*16 + lr)*40 + lg*8];
            acc[nt] = __builtin_amdgcn_mfma_f32_16x16x32_bf16(af, bf, acc[nt], 0, 0, 0);
        }
    }

    __syncthreads();
    #pragma unroll
    for (int nt = 0; nt < 4; nt++)
        #pragma unroll
        for (int r = 0; r < 4; r++)
            Cs[16*w + lg*4 + r][nt*16 + lr] = acc[nt][r];
    __syncthreads();

    const int tx = tid & 15, ty = tid >> 4;
    #pragma unroll
    for (int i = 0; i < 4; i++) {
        float4 o;
        o.x = Cs[ty*4 + i][tx*4 + 0];
        o.y = Cs[ty*4 + i][tx*4 + 1];
        o.z = Cs[ty*4 + i][tx*4 + 2];
        o.w = Cs[ty*4 + i][tx*4 + 3];
        *(float4*)&out[(size_t)(r0 + ty*4 + i) * DMODEL + c0 + tx*4] = o;
    }
}

// ---------------------------------------------------------------------------
extern "C" void kernel_launch(void* const* d_in, const int* in_sizes, int n_in,
                              void* d_out, int out_size, void* d_ws, size_t ws_size,
                              hipStream_t stream) {
    const float* x         = (const float*)d_in[0];
    const float* positions = (const float*)d_in[1];
    const float* Wq        = (const float*)d_in[2];
    const float* Wk        = (const float*)d_in[3];
    const float* Wv        = (const float*)d_in[4];
    const float* Wo        = (const float*)d_in[5];
    // d_in[6] = U : unused — QR of a full-rank square matrix is a complete
    // orthogonal basis, so P = Uq Uq^T = I and the projection is a no-op.
    const float* freqs     = (const float*)d_in[7];
    float* out = (float*)d_out;

    // workspace layout
    float*  ws    = (float*)d_ws;
    float*  cosT  = ws;                                 // 262144 f32
    float*  sinT  = cosT + NH*NSEQ*MHALF;               // 262144 f32
    float*  Opart = sinT + NH*NSEQ*MHALF;               // 2*2097152 f32
    float*  Lsum  = Opart + 2*(size_t)NBATCH*NH*NSEQ*DH;  // 2*32768 f32
    uint*   cnt   = (uint*)(Lsum + 2*(size_t)NBATCH*NH*NSEQ);   // 512 u32
    ushort* xb    = (ushort*)(cnt + 512);               // 2M bf16
    ushort* Wt    = xb + (size_t)MROWS*DMODEL;          // 2048*512 bf16
    ushort* Qb    = Wt + (size_t)2048*DMODEL;
    ushort* Kb    = Qb + (size_t)NBATCH*NH*NSEQ*DH;
    ushort* Vt    = Kb + (size_t)NBATCH*NH*NSEQ*DH;
    ushort* Obb   = Vt + (size_t)NBATCH*NH*NSEQ*DH;

    prep_kernel<<<dim3(2304), 256, 0, stream>>>(positions, freqs, x, Wq, Wk, Wv, Wo,
                                                cosT, sinT, xb, Wt, cnt);
    qkv_gemm<<<dim3(24, 64), 256, 0, stream>>>(xb, Wt, cosT, sinT, Qb, Kb, Vt);
    attn_kernel<<<dim3(16, 32, 2), 256, 0, stream>>>(Qb, Kb, Vt, Opart, Lsum, cnt, Obb);
    out_gemm<<<dim3(8, 64), 256, 0, stream>>>(Obb, Wt, out);
}

// Round 9
// 132.049 us; speedup vs baseline: 2.2658x; 2.2658x over previous
//
#include <hip/hip_runtime.h>
#include <math.h>

#define NBATCH 4
#define NSEQ   1024
#define DMODEL 512
#define NH     8
#define DH     64
#define MROWS  (NBATCH*NSEQ)   // 4096
#define MHALF  (DH/2)          // 32

typedef __attribute__((ext_vector_type(8))) short bf16x8;
typedef __attribute__((ext_vector_type(4))) float floatx4;

// round-to-nearest-even fp32 -> bf16 (finite inputs only)
__device__ __forceinline__ ushort f2bf(float f) {
    union { float f; uint u; } v; v.f = f;
    uint r = v.u + 0x7fffu + ((v.u >> 16) & 1u);
    return (ushort)(r >> 16);
}

// ---------------------------------------------------------------------------
// Kernel 0 (fused prep): blocks 0..1023 angles, 1024..2047 x->bf16,
// 2048..2303 weight transpose-cast into Wt[n_global][k] bf16
// (0..511 Wq, 512..1023 Wk, 1024..1535 Wv, 1536..2047 Wo).
// ---------------------------------------------------------------------------
__global__ __launch_bounds__(256) void prep_kernel(
    const float* __restrict__ pos, const float* __restrict__ freqs,
    const float* __restrict__ x,
    const float* __restrict__ Wq, const float* __restrict__ Wk,
    const float* __restrict__ Wv, const float* __restrict__ Wo,
    float* __restrict__ cosT, float* __restrict__ sinT,
    ushort* __restrict__ xb, ushort* __restrict__ Wt)
{
    __shared__ float T[64][65];
    const int bid = blockIdx.x;
    const int tid = threadIdx.x;

    if (bid < 1024) {
        int idx = bid * 256 + tid;
        int m = idx & 31;
        int n = (idx >> 5) & 1023;
        int h = idx >> 15;
        float a = pos[n*2+0] * freqs[(h*MHALF+m)*2+0]
                + pos[n*2+1] * freqs[(h*MHALF+m)*2+1];
        cosT[idx] = cosf(a);
        sinT[idx] = sinf(a);
    } else if (bid < 2048) {
        int idx = ((bid - 1024) * 256 + tid) * 8;
        float4 a = *(const float4*)&x[idx];
        float4 b = *(const float4*)&x[idx+4];
        uint4 pk;
        pk.x = (uint)f2bf(a.x) | ((uint)f2bf(a.y) << 16);
        pk.y = (uint)f2bf(a.z) | ((uint)f2bf(a.w) << 16);
        pk.z = (uint)f2bf(b.x) | ((uint)f2bf(b.y) << 16);
        pk.w = (uint)f2bf(b.z) | ((uint)f2bf(b.w) << 16);
        *(uint4*)&xb[idx] = pk;
    } else {
        int b2 = bid - 2048;               // 0..255
        int n0g = (b2 & 31) * 64;          // 0..2047
        int k0  = (b2 >> 5) * 64;
        int mat = n0g >> 9;
        const float* W = (mat == 0) ? Wq : ((mat == 1) ? Wk : ((mat == 2) ? Wv : Wo));
        int n0 = n0g & 511;
        int c = tid & 63, r = tid >> 6;
        #pragma unroll
        for (int i = 0; i < 16; i++)
            T[r + i*4][c] = W[(k0 + r + i*4) * DMODEL + n0 + c];
        __syncthreads();
        int nl = tid >> 2;
        int kg = tid & 3;
        #pragma unroll
        for (int g = 0; g < 4; g++) {
            int kl = kg * 16 + g * 4;
            uint2 pk;
            pk.x = (uint)f2bf(T[kl+0][nl]) | ((uint)f2bf(T[kl+1][nl]) << 16);
            pk.y = (uint)f2bf(T[kl+2][nl]) | ((uint)f2bf(T[kl+3][nl]) << 16);
            *(uint2*)&Wt[(size_t)(n0g + nl) * DMODEL + k0 + kl] = pk;
        }
    }
}

// ---------------------------------------------------------------------------
// Kernel 1: QKV GEMM via bf16 MFMA + rotary + bf16 pack + V-transpose.
// (R3 64x64-tile version — verified; grid (24,64) = 1536 blocks.)
// ---------------------------------------------------------------------------
__global__ __launch_bounds__(256) void qkv_gemm(
    const ushort* __restrict__ xb, const ushort* __restrict__ Wt,
    const float* __restrict__ cosT, const float* __restrict__ sinT,
    ushort* __restrict__ Qb, ushort* __restrict__ Kb, ushort* __restrict__ Vt)
{
    __shared__ ushort As[64 * 40];
    __shared__ ushort Bs[64 * 40];
    __shared__ float  Cs[64][65];

    const int cb = blockIdx.x;           // 0..23
    const int rb = blockIdx.y;           // 0..63
    const int mat = cb >> 3;             // 0=Q 1=K 2=V
    const int c0 = (cb & 7) * 64;
    const int r0 = rb * 64;
    const int ng0 = mat * 512 + c0;

    const int tid = threadIdx.x;
    const int w = tid >> 6, l = tid & 63;
    const int lr = l & 15, lg = l >> 4;

    const int srow = tid >> 2;
    const int sgrp = tid & 3;

    floatx4 acc[4];
    #pragma unroll
    for (int nt = 0; nt < 4; nt++) acc[nt] = (floatx4){0.f,0.f,0.f,0.f};

    for (int k0 = 0; k0 < DMODEL; k0 += 32) {
        __syncthreads();
        *(uint4*)&As[srow*40 + sgrp*8] =
            *(const uint4*)&xb[(size_t)(r0 + srow) * DMODEL + k0 + sgrp*8];
        *(uint4*)&Bs[srow*40 + sgrp*8] =
            *(const uint4*)&Wt[(size_t)(ng0 + srow) * DMODEL + k0 + sgrp*8];
        __syncthreads();

        bf16x8 af = *(const bf16x8*)&As[(16*w + lr)*40 + lg*8];
        #pragma unroll
        for (int nt = 0; nt < 4; nt++) {
            bf16x8 bf = *(const bf16x8*)&Bs[(nt*16 + lr)*40 + lg*8];
            acc[nt] = __builtin_amdgcn_mfma_f32_16x16x32_bf16(af, bf, acc[nt], 0, 0, 0);
        }
    }

    __syncthreads();
    #pragma unroll
    for (int nt = 0; nt < 4; nt++)
        #pragma unroll
        for (int r = 0; r < 4; r++)
            Cs[16*w + lg*4 + r][nt*16 + lr] = acc[nt][r];
    __syncthreads();

    const int tx = tid & 15, ty = tid >> 4;
    const int dbase = tx * 4;
    const int head = c0 >> 6;

    if (mat == 2) {
        int rowbase = r0 + ty * 4;
        int b = rowbase >> 10, n0 = rowbase & 1023;
        size_t vbase = (size_t)(b * NH + head) * DH;
        #pragma unroll
        for (int j = 0; j < 4; j++) {
            ushort us[4];
            #pragma unroll
            for (int i = 0; i < 4; i++) us[i] = f2bf(Cs[ty*4 + i][tx*4 + j]);
            uint2 pk;
            pk.x = (uint)us[0] | ((uint)us[1] << 16);
            pk.y = (uint)us[2] | ((uint)us[3] << 16);
            *(uint2*)&Vt[(vbase + dbase + j) * NSEQ + n0] = pk;
        }
    } else {
        ushort* dst = (mat == 0) ? Qb : Kb;
        #pragma unroll
        for (int i = 0; i < 4; i++) {
            int row = r0 + ty * 4 + i;
            int b = row >> 10, n = row & 1023;
            float v[4];
            #pragma unroll
            for (int p = 0; p < 2; p++) {
                int de = dbase + 2 * p;
                int m = de >> 1;
                float c = cosT[(head * NSEQ + n) * MHALF + m];
                float s = sinT[(head * NSEQ + n) * MHALF + m];
                float ve = Cs[ty*4 + i][tx*4 + 2*p];
                float vo = Cs[ty*4 + i][tx*4 + 2*p + 1];
                v[2*p]     = ve * c - vo * s;
                v[2*p + 1] = ve * s + vo * c;
            }
            uint2 pk;
            pk.x = (uint)f2bf(v[0]) | ((uint)f2bf(v[1]) << 16);
            pk.y = (uint)f2bf(v[2]) | ((uint)f2bf(v[3]) << 16);
            *(uint2*)&dst[((size_t)(b * NH + head) * NSEQ + n) * DH + dbase] = pk;
        }
    }
}

// ---------------------------------------------------------------------------
// Kernel 2: flash attention, split-K x2, no-rescale softmax (R4 structure,
// R5-verified math). Grid (16, 32, 2) = 1024 blocks, 4 blocks/CU.
// Scores |s| <~ 8 << 88 so exp2(c*s) cannot overflow; p,l unnormalized.
// No fences/atomics — the combine runs as a separate kernel (stream order).
// ---------------------------------------------------------------------------
__global__ __launch_bounds__(256, 4) void attn_kernel(
    const ushort* __restrict__ Qb, const ushort* __restrict__ Kb,
    const ushort* __restrict__ Vt, float* __restrict__ Opart,
    float* __restrict__ Lsum)
{
    __shared__ ushort Ks[64 * 72];
    __shared__ ushort Vs[64 * 72];
    __shared__ ushort Ps[64 * 72];

    const int tid = threadIdx.x;
    const int w = tid >> 6, l = tid & 63;
    const int lr = l & 15, lg = l >> 4;
    const int bh = blockIdx.y, q0 = blockIdx.x * 64;
    const int z = blockIdx.z, jt0 = z * 8;

    const ushort* Qg = Qb + (size_t)bh * NSEQ * DH;
    const ushort* Kg = Kb + (size_t)bh * NSEQ * DH;
    const ushort* Vg = Vt + (size_t)bh * DH * NSEQ;

    bf16x8 qf[2];
    #pragma unroll
    for (int ks = 0; ks < 2; ks++)
        qf[ks] = *(const bf16x8*)(Qg + (size_t)(q0 + 16*w + lr) * DH + ks*32 + lg*8);

    floatx4 ot[4];
    #pragma unroll
    for (int i = 0; i < 4; i++) ot[i] = (floatx4){0.f, 0.f, 0.f, 0.f};
    float rsum = 0.f;
    const float cexp = 0.2550348550f;    // log2(e)/sqrt(32)

    const int sr = tid >> 2;
    const int sc = (tid & 3) * 16;

    // prefetch first tile
    const ushort* kp = Kg + (size_t)(jt0*64 + sr) * DH + sc;
    uint4 ka  = *(const uint4*)kp;
    uint4 kb2 = *(const uint4*)(kp + 8);
    const ushort* vp = Vg + (size_t)sr * NSEQ + jt0*64 + sc;
    uint4 va  = *(const uint4*)vp;
    uint4 vb2 = *(const uint4*)(vp + 8);

    for (int jt = jt0; jt < jt0 + 8; jt++) {
        __syncthreads();
        *(uint4*)&Ks[sr*72 + sc]     = ka;
        *(uint4*)&Ks[sr*72 + sc + 8] = kb2;
        *(uint4*)&Vs[sr*72 + sc]     = va;
        *(uint4*)&Vs[sr*72 + sc + 8] = vb2;
        __syncthreads();

        if (jt < jt0 + 7) {   // prefetch next tile (uniform branch)
            const ushort* kn = Kg + (size_t)((jt+1)*64 + sr) * DH + sc;
            ka  = *(const uint4*)kn;
            kb2 = *(const uint4*)(kn + 8);
            const ushort* vn = Vg + (size_t)sr * NSEQ + (jt+1)*64 + sc;
            va  = *(const uint4*)vn;
            vb2 = *(const uint4*)(vn + 8);
        }

        // S^T strip (raw scores) -> p = exp2(c*s) -> P^T pack (wave-local)
        #pragma unroll
        for (int jm = 0; jm < 4; jm++) {
            bf16x8 a0 = *(const bf16x8*)&Ks[(jm*16 + lr)*72 + lg*8];
            bf16x8 a1 = *(const bf16x8*)&Ks[(jm*16 + lr)*72 + 32 + lg*8];
            floatx4 s = (floatx4){0.f, 0.f, 0.f, 0.f};
            s = __builtin_amdgcn_mfma_f32_16x16x32_bf16(a0, qf[0], s, 0, 0, 0);
            s = __builtin_amdgcn_mfma_f32_16x16x32_bf16(a1, qf[1], s, 0, 0, 0);
            ushort us[4];
            #pragma unroll
            for (int r = 0; r < 4; r++) {
                float p = exp2f(s[r] * cexp);
                rsum += p;
                us[r] = f2bf(p);
            }
            uint2 pk;
            pk.x = (uint)us[0] | ((uint)us[1] << 16);
            pk.y = (uint)us[2] | ((uint)us[3] << 16);
            *(uint2*)&Ps[(16*w + lr)*72 + jm*16 + lg*4] = pk;
        }

        // PV: O^T[d][q] += V^T[d][j] * P^T[j][q]  (Ps rows wave-local)
        bf16x8 pf[2];
        #pragma unroll
        for (int ks = 0; ks < 2; ks++)
            pf[ks] = *(const bf16x8*)&Ps[(16*w + lr)*72 + ks*32 + lg*8];
        #pragma unroll
        for (int dt = 0; dt < 4; dt++) {
            bf16x8 v0 = *(const bf16x8*)&Vs[(dt*16 + lr)*72 + lg*8];
            bf16x8 v1 = *(const bf16x8*)&Vs[(dt*16 + lr)*72 + 32 + lg*8];
            ot[dt] = __builtin_amdgcn_mfma_f32_16x16x32_bf16(v0, pf[0], ot[dt], 0, 0, 0);
            ot[dt] = __builtin_amdgcn_mfma_f32_16x16x32_bf16(v1, pf[1], ot[dt], 0, 0, 0);
        }
    }

    // reduce l across the 4 lg-groups (disjoint j sets)
    rsum += __shfl_xor(rsum, 16, 64);
    rsum += __shfl_xor(rsum, 32, 64);

    const int n = q0 + 16*w + lr;
    const size_t obase = ((size_t)(z * 32 + bh) * NSEQ + n) * DH;
    #pragma unroll
    for (int dt = 0; dt < 4; dt++)
        *(floatx4*)&Opart[obase + dt*16 + lg*4] = ot[dt];
    if (lg == 0)
        Lsum[(size_t)(z * 32 + bh) * NSEQ + n] = rsum;
}

// ---------------------------------------------------------------------------
// Kernel 2b: combine the 2 split-K slices -> Obb bf16 [bh][n][d].
// No max-merge needed (no-rescale): O = (O0+O1) / (l0+l1).
// 4 threads per query row (16 d each); grid 512 x 256.
// ---------------------------------------------------------------------------
__global__ __launch_bounds__(256) void combine_kernel(
    const float* __restrict__ Op, const float* __restrict__ Ls,
    ushort* __restrict__ Obb)
{
    int idx = blockIdx.x * 256 + threadIdx.x;   // 0..131071
    int qi = idx >> 2;                          // bh*NSEQ + n
    int dp = (idx & 3) << 4;
    float inv = 1.f / (Ls[qi] + Ls[32768 + qi]);
    const float* p0 = Op + (size_t)qi * 64 + dp;
    const size_t zs = (size_t)32768 * 64;
    ushort* po = Obb + (size_t)qi * 64 + dp;
    #pragma unroll
    for (int g = 0; g < 4; g++) {
        float4 u0 = *(const float4*)(p0 + g*4);
        float4 u1 = *(const float4*)(p0 + zs + g*4);
        float sx = (u0.x + u1.x) * inv;
        float sy = (u0.y + u1.y) * inv;
        float sz = (u0.z + u1.z) * inv;
        float sw = (u0.w + u1.w) * inv;
        uint2 pk;
        pk.x = (uint)f2bf(sx) | ((uint)f2bf(sy) << 16);
        pk.y = (uint)f2bf(sz) | ((uint)f2bf(sw) << 16);
        *(uint2*)(po + g*4) = pk;
    }
}

// ---------------------------------------------------------------------------
// Kernel 3: output projection via bf16 MFMA (R4 version — verified).
// A gathered from Obb [bh][n][d] bf16; B = Wt rows 1536..2047. Grid (8,64).
// ---------------------------------------------------------------------------
__global__ __launch_bounds__(256) void out_gemm(
    const ushort* __restrict__ Obb, const ushort* __restrict__ Wt,
    float* __restrict__ out)
{
    __shared__ ushort As[64 * 40];
    __shared__ ushort Bs[64 * 40];
    __shared__ float  Cs[64][65];

    const int cb = blockIdx.x;
    const int rb = blockIdx.y;
    const int c0 = cb * 64, r0 = rb * 64;

    const int tid = threadIdx.x;
    const int w = tid >> 6, l = tid & 63;
    const int lr = l & 15, lg = l >> 4;
    const int srow = tid >> 2;
    const int sgrp = tid & 3;

    const int arow = r0 + srow;
    const int b = arow >> 10, n = arow & 1023;

    floatx4 acc[4];
    #pragma unroll
    for (int nt = 0; nt < 4; nt++) acc[nt] = (floatx4){0.f,0.f,0.f,0.f};

    for (int k0 = 0; k0 < DMODEL; k0 += 32) {
        int h = k0 >> 6;
        int d0 = k0 & 63;
        __syncthreads();
        *(uint4*)&As[srow*40 + sgrp*8] =
            *(const uint4*)&Obb[((size_t)(b * NH + h) * NSEQ + n) * DH + d0 + sgrp*8];
        *(uint4*)&Bs[srow*40 + sgrp*8] =
            *(const uint4*)&Wt[(size_t)(1536 + c0 + srow) * DMODEL + k0 + sgrp*8];
        __syncthreads();

        bf16x8 af = *(const bf16x8*)&As[(16*w + lr)*40 + lg*8];
        #pragma unroll
        for (int nt = 0; nt < 4; nt++) {
            bf16x8 bf = *(const bf16x8*)&Bs[(nt*16 + lr)*40 + lg*8];
            acc[nt] = __builtin_amdgcn_mfma_f32_16x16x32_bf16(af, bf, acc[nt], 0, 0, 0);
        }
    }

    __syncthreads();
    #pragma unroll
    for (int nt = 0; nt < 4; nt++)
        #pragma unroll
        for (int r = 0; r < 4; r++)
            Cs[16*w + lg*4 + r][nt*16 + lr] = acc[nt][r];
    __syncthreads();

    const int tx = tid & 15, ty = tid >> 4;
    #pragma unroll
    for (int i = 0; i < 4; i++) {
        float4 o;
        o.x = Cs[ty*4 + i][tx*4 + 0];
        o.y = Cs[ty*4 + i][tx*4 + 1];
        o.z = Cs[ty*4 + i][tx*4 + 2];
        o.w = Cs[ty*4 + i][tx*4 + 3];
        *(float4*)&out[(size_t)(r0 + ty*4 + i) * DMODEL + c0 + tx*4] = o;
    }
}

// ---------------------------------------------------------------------------
extern "C" void kernel_launch(void* const* d_in, const int* in_sizes, int n_in,
                              void* d_out, int out_size, void* d_ws, size_t ws_size,
                              hipStream_t stream) {
    const float* x         = (const float*)d_in[0];
    const float* positions = (const float*)d_in[1];
    const float* Wq        = (const float*)d_in[2];
    const float* Wk        = (const float*)d_in[3];
    const float* Wv        = (const float*)d_in[4];
    const float* Wo        = (const float*)d_in[5];
    // d_in[6] = U : unused — QR of a full-rank square matrix is a complete
    // orthogonal basis, so P = Uq Uq^T = I and the projection is a no-op.
    const float* freqs     = (const float*)d_in[7];
    float* out = (float*)d_out;

    // workspace layout
    float*  ws    = (float*)d_ws;
    float*  cosT  = ws;                                 // 262144 f32
    float*  sinT  = cosT + NH*NSEQ*MHALF;               // 262144 f32
    float*  Opart = sinT + NH*NSEQ*MHALF;               // 2*2097152 f32
    float*  Lsum  = Opart + 2*(size_t)NBATCH*NH*NSEQ*DH;  // 2*32768 f32
    ushort* xb    = (ushort*)(Lsum + 2*(size_t)NBATCH*NH*NSEQ);  // 2M bf16
    ushort* Wt    = xb + (size_t)MROWS*DMODEL;          // 2048*512 bf16
    ushort* Qb    = Wt + (size_t)2048*DMODEL;
    ushort* Kb    = Qb + (size_t)NBATCH*NH*NSEQ*DH;
    ushort* Vt    = Kb + (size_t)NBATCH*NH*NSEQ*DH;
    ushort* Obb   = Vt + (size_t)NBATCH*NH*NSEQ*DH;

    prep_kernel<<<dim3(2304), 256, 0, stream>>>(positions, freqs, x, Wq, Wk, Wv, Wo,
                                                cosT, sinT, xb, Wt);
    qkv_gemm<<<dim3(24, 64), 256, 0, stream>>>(xb, Wt, cosT, sinT, Qb, Kb, Vt);
    attn_kernel<<<dim3(16, 32, 2), 256, 0, stream>>>(Qb, Kb, Vt, Opart, Lsum);
    combine_kernel<<<dim3(512), 256, 0, stream>>>(Opart, Lsum, Obb);
    out_gemm<<<dim3(8, 64), 256, 0, stream>>>(Obb, Wt, out);
}